// Round 1
// 587.298 us; speedup vs baseline: 1.1517x; 1.1517x over previous
//
#include <hip/hip_runtime.h>

typedef unsigned short u16;
typedef __attribute__((ext_vector_type(8))) short bf16x8;
typedef __attribute__((ext_vector_type(4))) float f32x4;

__device__ inline float b2f(u16 u) {
  unsigned x = ((unsigned)u) << 16;
  return __uint_as_float(x);
}
__device__ inline u16 f2b(float f) {
  unsigned u = __float_as_uint(f);
  unsigned r = (u + 0x7fffu + ((u >> 16) & 1u)) >> 16;
  return (u16)r;
}

__device__ inline float wsum(float x) {
#pragma unroll
  for (int o = 32; o > 0; o >>= 1) x += __shfl_down(x, o);
  return x;
}

// async global->LDS, 16B per lane. LDS dest must be wave-uniform base + lane*16.
__device__ inline void gl16(const u16* g, u16* l) {
  __builtin_amdgcn_global_load_lds((const __attribute__((address_space(1))) void*)g,
                                   (__attribute__((address_space(3))) void*)l, 16, 0, 0);
}

// ---------------- prep: q cast->bf16 (mode 0), LN(k) (mode 1), LN(v) (mode 2) ----------------
__global__ __launch_bounds__(256) void prep_kernel(const float* __restrict__ q,
                                                   const float* __restrict__ k,
                                                   const float* __restrict__ v,
                                                   const float* __restrict__ kg,
                                                   const float* __restrict__ kb,
                                                   const float* __restrict__ vg,
                                                   const float* __restrict__ vb,
                                                   u16* __restrict__ QB,
                                                   u16* __restrict__ LNK,
                                                   u16* __restrict__ LNV) {
  __shared__ float red[8];
  int blk = blockIdx.x;
  int mode = blk >> 12;  // block-uniform
  long base = (long)(blk & 4095) * 1024;
  int t = threadIdx.x;
  const float* x = mode == 0 ? q : (mode == 1 ? k : v);
  u16* y = mode == 0 ? QB : (mode == 1 ? LNK : LNV);
  float4 raw = *(const float4*)(x + base + t * 4);
  float vv[4] = {raw.x, raw.y, raw.z, raw.w};
  if (mode == 0) {
    u16 o[4];
#pragma unroll
    for (int i = 0; i < 4; i++) o[i] = f2b(vv[i]);
    *(uint2*)(y + base + t * 4) = *(uint2*)o;
    return;
  }
  const float* g = mode == 1 ? kg : vg;
  const float* bb = mode == 1 ? kb : vb;
  float s = 0.f, ss = 0.f;
#pragma unroll
  for (int i = 0; i < 4; i++) { s += vv[i]; ss += vv[i] * vv[i]; }
  s = wsum(s);
  ss = wsum(ss);
  int wid = t >> 6;
  if ((t & 63) == 0) { red[wid] = s; red[4 + wid] = ss; }
  __syncthreads();
  s = red[0] + red[1] + red[2] + red[3];
  ss = red[4] + red[5] + red[6] + red[7];
  float mean = s * (1.f / 1024.f);
  float var = ss * (1.f / 1024.f) - mean * mean;
  float inv = rsqrtf(var + 1e-5f);
  float4 gv = *(const float4*)(g + t * 4);
  float4 bv = *(const float4*)(bb + t * 4);
  float gg[4] = {gv.x, gv.y, gv.z, gv.w};
  float b2[4] = {bv.x, bv.y, bv.z, bv.w};
  u16 outr[4];
#pragma unroll
  for (int i = 0; i < 4; i++) outr[i] = f2b((vv[i] - mean) * inv * gg[i] + b2[i]);
  *(uint2*)(y + base + t * 4) = *(uint2*)outr;
}

// ---------------- 4x fused 1024x1024 transpose, fp32 -> bf16 ----------------
__global__ __launch_bounds__(256) void transpose_w4(const float* __restrict__ W0,
                                                    const float* __restrict__ W1,
                                                    const float* __restrict__ W2,
                                                    const float* __restrict__ W3,
                                                    u16* __restrict__ T0, u16* __restrict__ T1,
                                                    u16* __restrict__ T2, u16* __restrict__ T3) {
  int z = blockIdx.z;
  const float* src = z == 0 ? W0 : (z == 1 ? W1 : (z == 2 ? W2 : W3));
  u16* dst = z == 0 ? T0 : (z == 1 ? T1 : (z == 2 ? T2 : T3));
  __shared__ u16 tile[32][33];
  int tx = threadIdx.x & 31, ty = threadIdx.x >> 5;
  int x = blockIdx.x * 32 + tx;
  int y0 = blockIdx.y * 32;
#pragma unroll
  for (int i = 0; i < 32; i += 8) tile[ty + i][tx] = f2b(src[(long)(y0 + ty + i) * 1024 + x]);
  __syncthreads();
  int X = blockIdx.y * 32 + tx;
  int Y0 = blockIdx.x * 32;
#pragma unroll
  for (int i = 0; i < 32; i += 8) dst[(long)(Y0 + ty + i) * 1024 + X] = tile[tx][ty + i];
}

// ------- per-(b,h) transpose of vp[b,c,h*64+dh] (bf16) -> vT[(b*16+h), dh, c] -------
__global__ __launch_bounds__(256) void transpose_v(const u16* __restrict__ vp,
                                                   u16* __restrict__ vT) {
  int z = blockIdx.z;
  const u16* src = vp + (long)(z >> 4) * 1048576 + (long)(z & 15) * 64;
  u16* dst = vT + (long)z * 65536;
  __shared__ u16 tile[32][33];
  int tx = threadIdx.x & 31, ty = threadIdx.x >> 5;
  int c0 = blockIdx.x * 32, d0 = blockIdx.y * 32;
#pragma unroll
  for (int i = 0; i < 32; i += 8) tile[ty + i][tx] = src[(long)(c0 + ty + i) * 1024 + d0 + tx];
  __syncthreads();
#pragma unroll
  for (int i = 0; i < 32; i += 8) dst[(long)(d0 + ty + i) * 1024 + c0 + tx] = tile[tx][ty + i];
}

// ---------------- MFMA GEMM core (m97 structure: global_load_lds staging) ----------------
// C[M,N] = A[M,K=1024] * Bt[N,K]^T + bias. All ld = 1024.
template <int BM, int BN, typename TC>
__device__ __forceinline__ void gemm_core(const u16* __restrict__ Ab,
                                          const u16* __restrict__ Bb,
                                          const float* __restrict__ bias,
                                          TC* __restrict__ Cb, long m0, long n0) {
  constexpr int TM = BM / 32;
  constexpr int TN = BN / 32;
  __shared__ __align__(16) u16 lsA[BM * 32];
  __shared__ __align__(16) u16 lsB[BN * 32];

  int tid = threadIdx.x;
  int wid = tid >> 6;
  int lane = tid & 63;
  int wm = (wid >> 1) * (BM / 2);
  int wn = (wid & 1) * (BN / 2);
  int lm = lane & 15;
  int quad = lane >> 4;

  f32x4 acc[TM][TN];
#pragma unroll
  for (int i = 0; i < TM; i++)
#pragma unroll
    for (int j = 0; j < TN; j++) acc[i][j] = (f32x4){0.f, 0.f, 0.f, 0.f};

  for (int k0 = 0; k0 < 1024; k0 += 32) {
#pragma unroll
    for (int c = tid; c < BM * 4; c += 256)
      gl16(Ab + (m0 + (c >> 2)) * 1024 + k0 + (c & 3) * 8, &lsA[c * 8]);
#pragma unroll
    for (int c = tid; c < BN * 4; c += 256)
      gl16(Bb + (n0 + (c >> 2)) * 1024 + k0 + (c & 3) * 8, &lsB[c * 8]);
    __syncthreads();  // drains vmcnt (global_load_lds) per compiler barrier semantics
    bf16x8 af[TM], bfr[TN];
#pragma unroll
    for (int i = 0; i < TM; i++)
      af[i] = *(const bf16x8*)&lsA[(wm + i * 16 + lm) * 32 + quad * 8];
#pragma unroll
    for (int j = 0; j < TN; j++)
      bfr[j] = *(const bf16x8*)&lsB[(wn + j * 16 + lm) * 32 + quad * 8];
#pragma unroll
    for (int i = 0; i < TM; i++)
#pragma unroll
      for (int j = 0; j < TN; j++)
        acc[i][j] = __builtin_amdgcn_mfma_f32_16x16x32_bf16(af[i], bfr[j], acc[i][j], 0, 0, 0);
    __syncthreads();
  }

#pragma unroll
  for (int j = 0; j < TN; j++) {
    long n = n0 + wn + j * 16 + lm;
    float bv = bias ? bias[n] : 0.f;
#pragma unroll
    for (int i = 0; i < TM; i++) {
      long mb = m0 + wm + i * 16 + quad * 4;
#pragma unroll
      for (int r = 0; r < 4; r++) {
        float val = acc[i][j][r] + bv;
        if constexpr (sizeof(TC) == 2) Cb[(mb + r) * 1024 + n] = f2b(val);
        else Cb[(mb + r) * 1024 + n] = val;
      }
    }
  }
}

struct QKVArgs {
  const u16* A[3];
  const u16* B[3];
  const float* b[3];
  u16* C[3];
};

// q/k/v projections batched over grid.z -> 768 blocks (3 blocks/CU) for overlap
__global__ __launch_bounds__(256) void gemm_qkv(QKVArgs g) {
  int z = blockIdx.z;
  gemm_core<128, 128, u16>(g.A[z], g.B[z], g.b[z], g.C[z], (long)blockIdx.x * 128,
                           (long)blockIdx.y * 128);
}

__global__ __launch_bounds__(256) void gemm_o(const u16* __restrict__ A,
                                              const u16* __restrict__ Bt,
                                              const float* __restrict__ bias,
                                              float* __restrict__ C) {
  gemm_core<128, 128, float>(A, Bt, bias, C, (long)blockIdx.x * 128, (long)blockIdx.y * 128);
}

// ---------------- fused attention: scores + gelu + softmax (in-register) + P·V ----------------
// grid (64 q-tiles, 64 z). One block: 16 Q-rows x full 1024 keys.
// Scores stay in registers (thread (lm,quad) of wave wid owns rows quad*4+r,
// cols wid*256 + jj*16 + lm). Max/sum via 16-lane shfl butterflies + tiny LDS combine.
__global__ __launch_bounds__(256) void fused_attn(const u16* __restrict__ QP,
                                                  const u16* __restrict__ KP,
                                                  const u16* __restrict__ VT,
                                                  float* __restrict__ attn,
                                                  u16* __restrict__ CTX) {
  __shared__ __align__(16) u16 P[16 * 1032];  // bf16 probabilities for PV
  __shared__ __align__(16) u16 qt[16 * 72];
  __shared__ float wredm[4][16];
  __shared__ float wreds[4][16];

  int z = blockIdx.y;
  int b = z >> 4, h = z & 15;
  long q0 = (long)blockIdx.x * 16;
  int tid = threadIdx.x;
  int wid = tid >> 6, lane = tid & 63;
  int lm = lane & 15, quad = lane >> 4;

  const u16* Qb = QP + (long)b * 1048576 + (long)h * 64;
  const u16* Kb = KP + (long)b * 1048576 + (long)h * 64;
  const u16* Vz = VT + (long)z * 65536;
  float* Az = attn + (long)z * 1048576;

  // stage Q tile 16x64 (bf16)
  if (tid < 128) {
    int row = tid >> 3, col8 = (tid & 7) * 8;
    *(uint4*)&qt[row * 72 + col8] = *(const uint4*)(Qb + (q0 + row) * 1024 + col8);
  }
  __syncthreads();

  bf16x8 af0 = *(const bf16x8*)&qt[lm * 72 + quad * 8];
  bf16x8 af1 = *(const bf16x8*)&qt[lm * 72 + 32 + quad * 8];

  int ncol0 = wid * 256;
  float gl[16][4];  // fully-unrolled static indexing only (no scratch)
  float mx[4] = {-1e30f, -1e30f, -1e30f, -1e30f};
#pragma unroll
  for (int jj = 0; jj < 16; jj++) {
    const u16* kr = Kb + (long)(ncol0 + jj * 16 + lm) * 1024;
    bf16x8 bf0 = *(const bf16x8*)(kr + quad * 8);
    bf16x8 bf1 = *(const bf16x8*)(kr + 32 + quad * 8);
    f32x4 s = (f32x4){0.f, 0.f, 0.f, 0.f};
    s = __builtin_amdgcn_mfma_f32_16x16x32_bf16(af0, bf0, s, 0, 0, 0);
    s = __builtin_amdgcn_mfma_f32_16x16x32_bf16(af1, bf1, s, 0, 0, 0);
#pragma unroll
    for (int r = 0; r < 4; r++) {
      float x = s[r];
      float g = 0.0625f * x * (1.f + erff(x * 0.70710678118654752f));  // gelu(x)*0.125
      gl[jj][r] = g;
      mx[r] = fmaxf(mx[r], g);
    }
  }

  // row max: butterfly across the 16-lane lm-group, combine 4 waves via LDS
#pragma unroll
  for (int r = 0; r < 4; r++) {
#pragma unroll
    for (int d = 1; d < 16; d <<= 1) mx[r] = fmaxf(mx[r], __shfl_xor(mx[r], d));
  }
  if (lm == 0) {
#pragma unroll
    for (int r = 0; r < 4; r++) wredm[wid][quad * 4 + r] = mx[r];
  }
  __syncthreads();
  float m[4], sum[4];
#pragma unroll
  for (int r = 0; r < 4; r++) {
    int row = quad * 4 + r;
    m[r] = fmaxf(fmaxf(wredm[0][row], wredm[1][row]), fmaxf(wredm[2][row], wredm[3][row]));
    sum[r] = 0.f;
  }
  // exp once, accumulate row sums
#pragma unroll
  for (int jj = 0; jj < 16; jj++) {
#pragma unroll
    for (int r = 0; r < 4; r++) {
      float e = __expf(gl[jj][r] - m[r]);
      gl[jj][r] = e;
      sum[r] += e;
    }
  }
#pragma unroll
  for (int r = 0; r < 4; r++) {
#pragma unroll
    for (int d = 1; d < 16; d <<= 1) sum[r] += __shfl_xor(sum[r], d);
  }
  if (lm == 0) {
#pragma unroll
    for (int r = 0; r < 4; r++) wreds[wid][quad * 4 + r] = sum[r];
  }
  __syncthreads();
  float inv[4];
#pragma unroll
  for (int r = 0; r < 4; r++) {
    int row = quad * 4 + r;
    inv[r] = 1.f / (wreds[0][row] + wreds[1][row] + wreds[2][row] + wreds[3][row]);
  }

  // write attn (fp32, from fp32 scores) + P (bf16) straight from registers
#pragma unroll
  for (int jj = 0; jj < 16; jj++) {
    int n = ncol0 + jj * 16 + lm;
#pragma unroll
    for (int r = 0; r < 4; r++) {
      float val = gl[jj][r] * inv[r];
      int row = quad * 4 + r;
      Az[(q0 + row) * 1024 + n] = val;
      P[row * 1032 + n] = f2b(val);
    }
  }
  __syncthreads();

  // ---- P·V: wave wid owns dh tile [wid*16, wid*16+16) ----
  {
    f32x4 acc = (f32x4){0.f, 0.f, 0.f, 0.f};
    const u16* Vrow = Vz + (long)(wid * 16 + lm) * 1024;
#pragma unroll 4
    for (int kc = 0; kc < 1024; kc += 32) {
      bf16x8 a = *(const bf16x8*)&P[lm * 1032 + kc + quad * 8];
      bf16x8 bv = *(const bf16x8*)(Vrow + kc + quad * 8);
      acc = __builtin_amdgcn_mfma_f32_16x16x32_bf16(a, bv, acc, 0, 0, 0);
    }
    int n = wid * 16 + lm;
    u16* Cb = CTX + (long)b * 1048576 + (long)h * 64;
#pragma unroll
    for (int r = 0; r < 4; r++) {
      Cb[(q0 + quad * 4 + r) * 1024 + n] = f2b(acc[r]);
    }
  }
}

// ---------------- row-wise L2 normalize (fp32) ----------------
__global__ __launch_bounds__(256) void l2norm_kernel(const float* __restrict__ o,
                                                     float* __restrict__ out) {
  long base = (long)blockIdx.x * 1024;
  int t = threadIdx.x;
  float4 raw = *(const float4*)(o + base + t * 4);
  float v[4] = {raw.x, raw.y, raw.z, raw.w};
  float ss = 0.f;
#pragma unroll
  for (int i = 0; i < 4; i++) ss += v[i] * v[i];
  ss = wsum(ss);
  __shared__ float red[4];
  int wid = t >> 6;
  if ((t & 63) == 0) red[wid] = ss;
  __syncthreads();
  ss = red[0] + red[1] + red[2] + red[3];
  float inv = 1.f / fmaxf(sqrtf(ss), 1e-12f);
  float4 outr = {v[0] * inv, v[1] * inv, v[2] * inv, v[3] * inv};
  *(float4*)(out + base + t * 4) = outr;
}

extern "C" void kernel_launch(void* const* d_in, const int* in_sizes, int n_in,
                              void* d_out, int out_size, void* d_ws, size_t ws_size,
                              hipStream_t stream) {
  const float* q = (const float*)d_in[0];
  const float* k = (const float*)d_in[1];
  const float* v = (const float*)d_in[2];
  const float* ln_k_g = (const float*)d_in[3];
  const float* ln_k_b = (const float*)d_in[4];
  const float* ln_v_g = (const float*)d_in[5];
  const float* ln_v_b = (const float*)d_in[6];
  const float* Wq = (const float*)d_in[7];
  const float* bq = (const float*)d_in[8];
  const float* Wk = (const float*)d_in[9];
  const float* bk = (const float*)d_in[10];
  const float* Wv = (const float*)d_in[11];
  const float* bv_ = (const float*)d_in[12];
  const float* Wo = (const float*)d_in[13];
  const float* bo = (const float*)d_in[14];

  const long MEG = 1024 * 1024;
  u16* ws16 = (u16*)d_ws;
  u16* LNK = ws16;                 // dead after qkv gemm; reused as CTX
  u16* LNV = ws16 + 4 * MEG;       // dead after qkv gemm
  u16* WQT = ws16 + 8 * MEG;
  u16* WKT = ws16 + 9 * MEG;
  u16* WVT = ws16 + 10 * MEG;
  u16* WOT = ws16 + 11 * MEG;      // alive until final proj
  u16* QP  = ws16 + 12 * MEG;      // dead after fused -> OO (fp32, 12M..20M u16)
  u16* KP  = ws16 + 16 * MEG;      // dead after fused
  u16* VP  = ws16 + 20 * MEG;      // dead after transpose_v
  u16* VT  = ws16 + 24 * MEG;      // alive through fused
  u16* QB  = ws16 + 28 * MEG;      // q cast to bf16; dead after qkv gemm
  u16* CTX = LNK;
  float* OO = (float*)(ws16 + 12 * MEG);

  float* out = (float*)d_out;
  float* attn = out + 4 * MEG;

  // q cast + LN(k) + LN(v) in one launch
  prep_kernel<<<12288, 256, 0, stream>>>(q, k, v, ln_k_g, ln_k_b, ln_v_g, ln_v_b, QB, LNK, LNV);

  // 4 weight transposes in one launch
  transpose_w4<<<dim3(32, 32, 4), 256, 0, stream>>>(Wq, Wk, Wv, Wo, WQT, WKT, WVT, WOT);

  // q/k/v projections batched (768 blocks = 3 blocks/CU)
  QKVArgs ga;
  ga.A[0] = QB;  ga.A[1] = LNK; ga.A[2] = LNV;
  ga.B[0] = WQT; ga.B[1] = WKT; ga.B[2] = WVT;
  ga.b[0] = bq;  ga.b[1] = bk;  ga.b[2] = bv_;
  ga.C[0] = QP;  ga.C[1] = KP;  ga.C[2] = VP;
  gemm_qkv<<<dim3(32, 8, 3), 256, 0, stream>>>(ga);

  transpose_v<<<dim3(32, 2, 64), 256, 0, stream>>>(VP, VT);

  // fused scores+gelu+softmax+attn+PV
  fused_attn<<<dim3(64, 64), 256, 0, stream>>>(QP, KP, VT, attn, CTX);

  // output projection + bias -> fp32
  gemm_o<<<dim3(32, 8), 256, 0, stream>>>(CTX, WOT, bo, OO);

  l2norm_kernel<<<4096, 256, 0, stream>>>(OO, out);
}

// Round 3
// 520.057 us; speedup vs baseline: 1.3007x; 1.1293x over previous
//
#include <hip/hip_runtime.h>

typedef unsigned short u16;
typedef __attribute__((ext_vector_type(8))) short bf16x8;
typedef __attribute__((ext_vector_type(4))) float f32x4;

__device__ inline float b2f(u16 u) {
  unsigned x = ((unsigned)u) << 16;
  return __uint_as_float(x);
}
__device__ inline u16 f2b(float f) {
  unsigned u = __float_as_uint(f);
  unsigned r = (u + 0x7fffu + ((u >> 16) & 1u)) >> 16;
  return (u16)r;
}

__device__ inline float wsum(float x) {
#pragma unroll
  for (int o = 32; o > 0; o >>= 1) x += __shfl_down(x, o);
  return x;
}

// async global->LDS, 16B per lane. LDS dest must be wave-uniform base + lane*16.
__device__ inline void gl16(const u16* g, u16* l) {
  __builtin_amdgcn_global_load_lds((const __attribute__((address_space(1))) void*)g,
                                   (__attribute__((address_space(3))) void*)l, 16, 0, 0);
}

// ---------------- prep: q cast->bf16 (mode 0), LN(k) (mode 1), LN(v) (mode 2) ----------------
__global__ __launch_bounds__(256) void prep_kernel(const float* __restrict__ q,
                                                   const float* __restrict__ k,
                                                   const float* __restrict__ v,
                                                   const float* __restrict__ kg,
                                                   const float* __restrict__ kb,
                                                   const float* __restrict__ vg,
                                                   const float* __restrict__ vb,
                                                   u16* __restrict__ QB,
                                                   u16* __restrict__ LNK,
                                                   u16* __restrict__ LNV) {
  __shared__ float red[8];
  int blk = blockIdx.x;
  int mode = blk >> 12;  // block-uniform
  long base = (long)(blk & 4095) * 1024;
  int t = threadIdx.x;
  const float* x = mode == 0 ? q : (mode == 1 ? k : v);
  u16* y = mode == 0 ? QB : (mode == 1 ? LNK : LNV);
  float4 raw = *(const float4*)(x + base + t * 4);
  float vv[4] = {raw.x, raw.y, raw.z, raw.w};
  if (mode == 0) {
    u16 o[4];
#pragma unroll
    for (int i = 0; i < 4; i++) o[i] = f2b(vv[i]);
    *(uint2*)(y + base + t * 4) = *(uint2*)o;
    return;
  }
  const float* g = mode == 1 ? kg : vg;
  const float* bb = mode == 1 ? kb : vb;
  float s = 0.f, ss = 0.f;
#pragma unroll
  for (int i = 0; i < 4; i++) { s += vv[i]; ss += vv[i] * vv[i]; }
  s = wsum(s);
  ss = wsum(ss);
  int wid = t >> 6;
  if ((t & 63) == 0) { red[wid] = s; red[4 + wid] = ss; }
  __syncthreads();
  s = red[0] + red[1] + red[2] + red[3];
  ss = red[4] + red[5] + red[6] + red[7];
  float mean = s * (1.f / 1024.f);
  float var = ss * (1.f / 1024.f) - mean * mean;
  float inv = rsqrtf(var + 1e-5f);
  float4 gv = *(const float4*)(g + t * 4);
  float4 bv = *(const float4*)(bb + t * 4);
  float gg[4] = {gv.x, gv.y, gv.z, gv.w};
  float b2[4] = {bv.x, bv.y, bv.z, bv.w};
  u16 outr[4];
#pragma unroll
  for (int i = 0; i < 4; i++) outr[i] = f2b((vv[i] - mean) * inv * gg[i] + b2[i]);
  *(uint2*)(y + base + t * 4) = *(uint2*)outr;
}

// ---------------- 4x fused 1024x1024 transpose, fp32 -> bf16 ----------------
__global__ __launch_bounds__(256) void transpose_w4(const float* __restrict__ W0,
                                                    const float* __restrict__ W1,
                                                    const float* __restrict__ W2,
                                                    const float* __restrict__ W3,
                                                    u16* __restrict__ T0, u16* __restrict__ T1,
                                                    u16* __restrict__ T2, u16* __restrict__ T3) {
  int z = blockIdx.z;
  const float* src = z == 0 ? W0 : (z == 1 ? W1 : (z == 2 ? W2 : W3));
  u16* dst = z == 0 ? T0 : (z == 1 ? T1 : (z == 2 ? T2 : T3));
  __shared__ u16 tile[32][33];
  int tx = threadIdx.x & 31, ty = threadIdx.x >> 5;
  int x = blockIdx.x * 32 + tx;
  int y0 = blockIdx.y * 32;
#pragma unroll
  for (int i = 0; i < 32; i += 8) tile[ty + i][tx] = f2b(src[(long)(y0 + ty + i) * 1024 + x]);
  __syncthreads();
  int X = blockIdx.y * 32 + tx;
  int Y0 = blockIdx.x * 32;
#pragma unroll
  for (int i = 0; i < 32; i += 8) dst[(long)(Y0 + ty + i) * 1024 + X] = tile[tx][ty + i];
}

// ------- per-(b,h) transpose of vp[b,c,h*64+dh] (bf16) -> vT[(b*16+h), dh, c] -------
__global__ __launch_bounds__(256) void transpose_v(const u16* __restrict__ vp,
                                                   u16* __restrict__ vT) {
  int z = blockIdx.z;
  const u16* src = vp + (long)(z >> 4) * 1048576 + (long)(z & 15) * 64;
  u16* dst = vT + (long)z * 65536;
  __shared__ u16 tile[32][33];
  int tx = threadIdx.x & 31, ty = threadIdx.x >> 5;
  int c0 = blockIdx.x * 32, d0 = blockIdx.y * 32;
#pragma unroll
  for (int i = 0; i < 32; i += 8) tile[ty + i][tx] = src[(long)(c0 + ty + i) * 1024 + d0 + tx];
  __syncthreads();
#pragma unroll
  for (int i = 0; i < 32; i += 8) dst[(long)(d0 + ty + i) * 1024 + c0 + tx] = tile[tx][ty + i];
}

// ---------------- MFMA GEMM core (m97 structure: global_load_lds staging) ----------------
// C[M,N] = A[M,K=1024] * Bt[N,K]^T + bias. All ld = 1024.
template <int BM, int BN, typename TC>
__device__ __forceinline__ void gemm_core(const u16* __restrict__ Ab,
                                          const u16* __restrict__ Bb,
                                          const float* __restrict__ bias,
                                          TC* __restrict__ Cb, long m0, long n0) {
  constexpr int TM = BM / 32;
  constexpr int TN = BN / 32;
  __shared__ __align__(16) u16 lsA[BM * 32];
  __shared__ __align__(16) u16 lsB[BN * 32];

  int tid = threadIdx.x;
  int wid = tid >> 6;
  int lane = tid & 63;
  int wm = (wid >> 1) * (BM / 2);
  int wn = (wid & 1) * (BN / 2);
  int lm = lane & 15;
  int quad = lane >> 4;

  f32x4 acc[TM][TN];
#pragma unroll
  for (int i = 0; i < TM; i++)
#pragma unroll
    for (int j = 0; j < TN; j++) acc[i][j] = (f32x4){0.f, 0.f, 0.f, 0.f};

  for (int k0 = 0; k0 < 1024; k0 += 32) {
#pragma unroll
    for (int c = tid; c < BM * 4; c += 256)
      gl16(Ab + (m0 + (c >> 2)) * 1024 + k0 + (c & 3) * 8, &lsA[c * 8]);
#pragma unroll
    for (int c = tid; c < BN * 4; c += 256)
      gl16(Bb + (n0 + (c >> 2)) * 1024 + k0 + (c & 3) * 8, &lsB[c * 8]);
    __syncthreads();  // drains vmcnt (global_load_lds) per compiler barrier semantics
    bf16x8 af[TM], bfr[TN];
#pragma unroll
    for (int i = 0; i < TM; i++)
      af[i] = *(const bf16x8*)&lsA[(wm + i * 16 + lm) * 32 + quad * 8];
#pragma unroll
    for (int j = 0; j < TN; j++)
      bfr[j] = *(const bf16x8*)&lsB[(wn + j * 16 + lm) * 32 + quad * 8];
#pragma unroll
    for (int i = 0; i < TM; i++)
#pragma unroll
      for (int j = 0; j < TN; j++)
        acc[i][j] = __builtin_amdgcn_mfma_f32_16x16x32_bf16(af[i], bfr[j], acc[i][j], 0, 0, 0);
    __syncthreads();
  }

#pragma unroll
  for (int j = 0; j < TN; j++) {
    long n = n0 + wn + j * 16 + lm;
    float bv = bias ? bias[n] : 0.f;
#pragma unroll
    for (int i = 0; i < TM; i++) {
      long mb = m0 + wm + i * 16 + quad * 4;
#pragma unroll
      for (int r = 0; r < 4; r++) {
        float val = acc[i][j][r] + bv;
        if constexpr (sizeof(TC) == 2) Cb[(mb + r) * 1024 + n] = f2b(val);
        else Cb[(mb + r) * 1024 + n] = val;
      }
    }
  }
}

struct QKVArgs {
  const u16* A[3];
  const u16* B[3];
  const float* b[3];
  u16* C[3];
};

// q/k/v projections batched over grid.z -> 768 blocks (3 blocks/CU) for overlap
__global__ __launch_bounds__(256) void gemm_qkv(QKVArgs g) {
  int z = blockIdx.z;
  gemm_core<128, 128, u16>(g.A[z], g.B[z], g.b[z], g.C[z], (long)blockIdx.x * 128,
                           (long)blockIdx.y * 128);
}

__global__ __launch_bounds__(256) void gemm_o(const u16* __restrict__ A,
                                              const u16* __restrict__ Bt,
                                              const float* __restrict__ bias,
                                              float* __restrict__ C) {
  gemm_core<128, 128, float>(A, Bt, bias, C, (long)blockIdx.x * 128, (long)blockIdx.y * 128);
}

// ---------------- fused attention v3 ----------------
// grid (64 q-tiles, 64 z). One block: 16 Q-rows x full 1024 keys.
// Score loop: exp(gelu(x)*0.125) computed immediately (NO max pass: logits in
// [-0.022, ~3] by construction, fp32-safe), unnormalized e -> LDS P (bf16),
// row sums in 4 regs. PV runs on unnormalized P, scales by rowinv in epilogue.
// attn output written from LDS in a coalesced f32x4 nontemporal pass.
__global__ __launch_bounds__(256) void fused_attn(const u16* __restrict__ QP,
                                                  const u16* __restrict__ KP,
                                                  const u16* __restrict__ VT,
                                                  float* __restrict__ attn,
                                                  u16* __restrict__ CTX) {
  __shared__ __align__(16) u16 P[16 * 1032];  // bf16 unnormalized exp
  __shared__ __align__(16) u16 qt[16 * 72];
  __shared__ float wreds[4][16];
  __shared__ float rowinv[16];

  int z = blockIdx.y;
  int b = z >> 4, h = z & 15;
  long q0 = (long)blockIdx.x * 16;
  int tid = threadIdx.x;
  int wid = tid >> 6, lane = tid & 63;
  int lm = lane & 15, quad = lane >> 4;

  const u16* Qb = QP + (long)b * 1048576 + (long)h * 64;
  const u16* Kb = KP + (long)b * 1048576 + (long)h * 64;
  const u16* Vz = VT + (long)z * 65536;
  float* Az = attn + (long)z * 1048576;

  // stage Q tile 16x64 (bf16)
  if (tid < 128) {
    int row = tid >> 3, col8 = (tid & 7) * 8;
    *(uint4*)&qt[row * 72 + col8] = *(const uint4*)(Qb + (q0 + row) * 1024 + col8);
  }
  __syncthreads();

  bf16x8 af0 = *(const bf16x8*)&qt[lm * 72 + quad * 8];
  bf16x8 af1 = *(const bf16x8*)&qt[lm * 72 + 32 + quad * 8];

  int ncol0 = wid * 256;
  float sum[4] = {0.f, 0.f, 0.f, 0.f};
#pragma unroll
  for (int jj = 0; jj < 16; jj++) {
    const u16* kr = Kb + (long)(ncol0 + jj * 16 + lm) * 1024;
    bf16x8 bf0 = *(const bf16x8*)(kr + quad * 8);
    bf16x8 bf1 = *(const bf16x8*)(kr + 32 + quad * 8);
    f32x4 s = (f32x4){0.f, 0.f, 0.f, 0.f};
    __builtin_amdgcn_s_setprio(1);
    s = __builtin_amdgcn_mfma_f32_16x16x32_bf16(af0, bf0, s, 0, 0, 0);
    s = __builtin_amdgcn_mfma_f32_16x16x32_bf16(af1, bf1, s, 0, 0, 0);
    __builtin_amdgcn_s_setprio(0);
    int n = ncol0 + jj * 16 + lm;
#pragma unroll
    for (int r = 0; r < 4; r++) {
      float x = s[r];
      // branchless erf (Abramowitz-Stegun 7.1.26, |err| <= 1.5e-7)
      float u = 0.70710678118654752f * x;
      float a = fabsf(u);
      float t = __builtin_amdgcn_rcpf(fmaf(0.3275911f, a, 1.0f));
      float p = t * fmaf(t, fmaf(t, fmaf(t, fmaf(t, 1.061405429f, -1.453152027f),
                                         1.421413741f), -0.284496736f), 0.254829592f);
      float eq = __expf(-a * a);
      float erfa = fmaf(-p, eq, 1.0f);
      float erfu = copysignf(erfa, u);
      float hx = 0.0625f * x;                 // 0.5*x*0.125
      float logit = fmaf(hx, erfu, hx);       // gelu(x)*0.125
      float e = __expf(logit);                // no max-subtraction (range-safe)
      sum[r] += e;
      P[(quad * 4 + r) * 1032 + n] = f2b(e);
    }
  }

  // row sums: butterfly across the 16-lane lm-group, combine 4 waves via LDS
#pragma unroll
  for (int r = 0; r < 4; r++) {
#pragma unroll
    for (int d = 1; d < 16; d <<= 1) sum[r] += __shfl_xor(sum[r], d);
  }
  if (lm == 0) {
#pragma unroll
    for (int r = 0; r < 4; r++) wreds[wid][quad * 4 + r] = sum[r];
  }
  __syncthreads();
  if (tid < 16) rowinv[tid] = 1.f / (wreds[0][tid] + wreds[1][tid] + wreds[2][tid] + wreds[3][tid]);
  __syncthreads();

  // attn write: thread t owns cols 4t..4t+3 of every row; coalesced f32x4 nt stores
#pragma unroll
  for (int r = 0; r < 16; r++) {
    float inv = rowinv[r];
    uint2 raw = *(const uint2*)&P[r * 1032 + tid * 4];
    u16* pr = (u16*)&raw;
    f32x4 o;
    o[0] = b2f(pr[0]) * inv;
    o[1] = b2f(pr[1]) * inv;
    o[2] = b2f(pr[2]) * inv;
    o[3] = b2f(pr[3]) * inv;
    __builtin_nontemporal_store(o, (f32x4*)(Az + (q0 + r) * 1024 + tid * 4));
  }

  // ---- P·V on unnormalized P: wave wid owns dh tile [wid*16, wid*16+16) ----
  {
    f32x4 acc = (f32x4){0.f, 0.f, 0.f, 0.f};
    const u16* Vrow = Vz + (long)(wid * 16 + lm) * 1024;
#pragma unroll 4
    for (int kc = 0; kc < 1024; kc += 32) {
      bf16x8 a = *(const bf16x8*)&P[lm * 1032 + kc + quad * 8];
      bf16x8 bv = *(const bf16x8*)(Vrow + kc + quad * 8);
      __builtin_amdgcn_s_setprio(1);
      acc = __builtin_amdgcn_mfma_f32_16x16x32_bf16(a, bv, acc, 0, 0, 0);
      __builtin_amdgcn_s_setprio(0);
    }
    int n = wid * 16 + lm;
    u16* Cb = CTX + (long)b * 1048576 + (long)h * 64;
#pragma unroll
    for (int r = 0; r < 4; r++) {
      float val = acc[r] * rowinv[quad * 4 + r];  // late normalize
      Cb[(q0 + quad * 4 + r) * 1024 + n] = f2b(val);
    }
  }
}

// ---------------- row-wise L2 normalize (fp32) ----------------
__global__ __launch_bounds__(256) void l2norm_kernel(const float* __restrict__ o,
                                                     float* __restrict__ out) {
  long base = (long)blockIdx.x * 1024;
  int t = threadIdx.x;
  float4 raw = *(const float4*)(o + base + t * 4);
  float v[4] = {raw.x, raw.y, raw.z, raw.w};
  float ss = 0.f;
#pragma unroll
  for (int i = 0; i < 4; i++) ss += v[i] * v[i];
  ss = wsum(ss);
  __shared__ float red[4];
  int wid = t >> 6;
  if ((t & 63) == 0) red[wid] = ss;
  __syncthreads();
  ss = red[0] + red[1] + red[2] + red[3];
  float inv = 1.f / fmaxf(sqrtf(ss), 1e-12f);
  float4 outr = {v[0] * inv, v[1] * inv, v[2] * inv, v[3] * inv};
  *(float4*)(out + base + t * 4) = outr;
}

extern "C" void kernel_launch(void* const* d_in, const int* in_sizes, int n_in,
                              void* d_out, int out_size, void* d_ws, size_t ws_size,
                              hipStream_t stream) {
  const float* q = (const float*)d_in[0];
  const float* k = (const float*)d_in[1];
  const float* v = (const float*)d_in[2];
  const float* ln_k_g = (const float*)d_in[3];
  const float* ln_k_b = (const float*)d_in[4];
  const float* ln_v_g = (const float*)d_in[5];
  const float* ln_v_b = (const float*)d_in[6];
  const float* Wq = (const float*)d_in[7];
  const float* bq = (const float*)d_in[8];
  const float* Wk = (const float*)d_in[9];
  const float* bk = (const float*)d_in[10];
  const float* Wv = (const float*)d_in[11];
  const float* bv_ = (const float*)d_in[12];
  const float* Wo = (const float*)d_in[13];
  const float* bo = (const float*)d_in[14];

  const long MEG = 1024 * 1024;
  u16* ws16 = (u16*)d_ws;
  u16* LNK = ws16;                 // dead after qkv gemm; reused as CTX
  u16* LNV = ws16 + 4 * MEG;       // dead after qkv gemm
  u16* WQT = ws16 + 8 * MEG;
  u16* WKT = ws16 + 9 * MEG;
  u16* WVT = ws16 + 10 * MEG;
  u16* WOT = ws16 + 11 * MEG;      // alive until final proj
  u16* QP  = ws16 + 12 * MEG;      // dead after fused -> OO (fp32, 12M..20M u16)
  u16* KP  = ws16 + 16 * MEG;      // dead after fused
  u16* VP  = ws16 + 20 * MEG;      // dead after transpose_v
  u16* VT  = ws16 + 24 * MEG;      // alive through fused
  u16* QB  = ws16 + 28 * MEG;      // q cast to bf16; dead after qkv gemm
  u16* CTX = LNK;
  float* OO = (float*)(ws16 + 12 * MEG);

  float* out = (float*)d_out;
  float* attn = out + 4 * MEG;

  // q cast + LN(k) + LN(v) in one launch
  prep_kernel<<<12288, 256, 0, stream>>>(q, k, v, ln_k_g, ln_k_b, ln_v_g, ln_v_b, QB, LNK, LNV);

  // 4 weight transposes in one launch
  transpose_w4<<<dim3(32, 32, 4), 256, 0, stream>>>(Wq, Wk, Wv, Wo, WQT, WKT, WVT, WOT);

  // q/k/v projections batched (768 blocks = 3 blocks/CU)
  QKVArgs ga;
  ga.A[0] = QB;  ga.A[1] = LNK; ga.A[2] = LNV;
  ga.B[0] = WQT; ga.B[1] = WKT; ga.B[2] = WVT;
  ga.b[0] = bq;  ga.b[1] = bk;  ga.b[2] = bv_;
  ga.C[0] = QP;  ga.C[1] = KP;  ga.C[2] = VP;
  gemm_qkv<<<dim3(32, 8, 3), 256, 0, stream>>>(ga);

  transpose_v<<<dim3(32, 2, 64), 256, 0, stream>>>(VP, VT);

  // fused scores+gelu+softmax+attn+PV
  fused_attn<<<dim3(64, 64), 256, 0, stream>>>(QP, KP, VT, attn, CTX);

  // output projection + bias -> fp32
  gemm_o<<<dim3(32, 8), 256, 0, stream>>>(CTX, WOT, bo, OO);

  l2norm_kernel<<<4096, 256, 0, stream>>>(OO, out);
}

// Round 4
// 503.318 us; speedup vs baseline: 1.3439x; 1.0333x over previous
//
#include <hip/hip_runtime.h>

typedef unsigned short u16;
typedef __attribute__((ext_vector_type(8))) short bf16x8;
typedef __attribute__((ext_vector_type(4))) float f32x4;

__device__ inline float b2f(u16 u) {
  unsigned x = ((unsigned)u) << 16;
  return __uint_as_float(x);
}
__device__ inline u16 f2b(float f) {
  unsigned u = __float_as_uint(f);
  unsigned r = (u + 0x7fffu + ((u >> 16) & 1u)) >> 16;
  return (u16)r;
}

__device__ inline float wsum(float x) {
#pragma unroll
  for (int o = 32; o > 0; o >>= 1) x += __shfl_down(x, o);
  return x;
}

// async global->LDS, 16B per lane. LDS dest must be wave-uniform base + lane*16.
__device__ inline void gl16(const u16* g, u16* l) {
  __builtin_amdgcn_global_load_lds((const __attribute__((address_space(1))) void*)g,
                                   (__attribute__((address_space(3))) void*)l, 16, 0, 0);
}

// ---------------- prep: q cast->bf16 (mode 0), LN(k) (mode 1), LN(v) (mode 2) ----------------
__global__ __launch_bounds__(256) void prep_kernel(const float* __restrict__ q,
                                                   const float* __restrict__ k,
                                                   const float* __restrict__ v,
                                                   const float* __restrict__ kg,
                                                   const float* __restrict__ kb,
                                                   const float* __restrict__ vg,
                                                   const float* __restrict__ vb,
                                                   u16* __restrict__ QB,
                                                   u16* __restrict__ LNK,
                                                   u16* __restrict__ LNV) {
  __shared__ float red[8];
  int blk = blockIdx.x;
  int mode = blk >> 12;  // block-uniform
  long base = (long)(blk & 4095) * 1024;
  int t = threadIdx.x;
  const float* x = mode == 0 ? q : (mode == 1 ? k : v);
  u16* y = mode == 0 ? QB : (mode == 1 ? LNK : LNV);
  float4 raw = *(const float4*)(x + base + t * 4);
  float vv[4] = {raw.x, raw.y, raw.z, raw.w};
  if (mode == 0) {
    u16 o[4];
#pragma unroll
    for (int i = 0; i < 4; i++) o[i] = f2b(vv[i]);
    *(uint2*)(y + base + t * 4) = *(uint2*)o;
    return;
  }
  const float* g = mode == 1 ? kg : vg;
  const float* bb = mode == 1 ? kb : vb;
  float s = 0.f, ss = 0.f;
#pragma unroll
  for (int i = 0; i < 4; i++) { s += vv[i]; ss += vv[i] * vv[i]; }
  s = wsum(s);
  ss = wsum(ss);
  int wid = t >> 6;
  if ((t & 63) == 0) { red[wid] = s; red[4 + wid] = ss; }
  __syncthreads();
  s = red[0] + red[1] + red[2] + red[3];
  ss = red[4] + red[5] + red[6] + red[7];
  float mean = s * (1.f / 1024.f);
  float var = ss * (1.f / 1024.f) - mean * mean;
  float inv = rsqrtf(var + 1e-5f);
  float4 gv = *(const float4*)(g + t * 4);
  float4 bv = *(const float4*)(bb + t * 4);
  float gg[4] = {gv.x, gv.y, gv.z, gv.w};
  float b2[4] = {bv.x, bv.y, bv.z, bv.w};
  u16 outr[4];
#pragma unroll
  for (int i = 0; i < 4; i++) outr[i] = f2b((vv[i] - mean) * inv * gg[i] + b2[i]);
  *(uint2*)(y + base + t * 4) = *(uint2*)outr;
}

// ---------------- 4x fused 1024x1024 transpose, fp32 -> bf16 ----------------
__global__ __launch_bounds__(256) void transpose_w4(const float* __restrict__ W0,
                                                    const float* __restrict__ W1,
                                                    const float* __restrict__ W2,
                                                    const float* __restrict__ W3,
                                                    u16* __restrict__ T0, u16* __restrict__ T1,
                                                    u16* __restrict__ T2, u16* __restrict__ T3) {
  int z = blockIdx.z;
  const float* src = z == 0 ? W0 : (z == 1 ? W1 : (z == 2 ? W2 : W3));
  u16* dst = z == 0 ? T0 : (z == 1 ? T1 : (z == 2 ? T2 : T3));
  __shared__ u16 tile[32][33];
  int tx = threadIdx.x & 31, ty = threadIdx.x >> 5;
  int x = blockIdx.x * 32 + tx;
  int y0 = blockIdx.y * 32;
#pragma unroll
  for (int i = 0; i < 32; i += 8) tile[ty + i][tx] = f2b(src[(long)(y0 + ty + i) * 1024 + x]);
  __syncthreads();
  int X = blockIdx.y * 32 + tx;
  int Y0 = blockIdx.x * 32;
#pragma unroll
  for (int i = 0; i < 32; i += 8) dst[(long)(Y0 + ty + i) * 1024 + X] = tile[tx][ty + i];
}

// ---------------- MFMA GEMM core (m97 structure: global_load_lds staging) ----------------
// C[M,N] = A[M,K=1024] * Bt[N,K]^T + bias. All ld = 1024.
// TRANSV: write output transposed per (b,h): VT[(b*16+h)][dh][c] (for the V projection).
template <int BM, int BN, typename TC, bool TRANSV>
__device__ __forceinline__ void gemm_core(const u16* __restrict__ Ab,
                                          const u16* __restrict__ Bb,
                                          const float* __restrict__ bias,
                                          TC* __restrict__ Cb, long m0, long n0) {
  constexpr int TM = BM / 32;
  constexpr int TN = BN / 32;
  __shared__ __align__(16) u16 lsA[BM * 32];
  __shared__ __align__(16) u16 lsB[BN * 32];

  int tid = threadIdx.x;
  int wid = tid >> 6;
  int lane = tid & 63;
  int wm = (wid >> 1) * (BM / 2);
  int wn = (wid & 1) * (BN / 2);
  int lm = lane & 15;
  int quad = lane >> 4;

  f32x4 acc[TM][TN];
#pragma unroll
  for (int i = 0; i < TM; i++)
#pragma unroll
    for (int j = 0; j < TN; j++) acc[i][j] = (f32x4){0.f, 0.f, 0.f, 0.f};

  for (int k0 = 0; k0 < 1024; k0 += 32) {
#pragma unroll
    for (int c = tid; c < BM * 4; c += 256)
      gl16(Ab + (m0 + (c >> 2)) * 1024 + k0 + (c & 3) * 8, &lsA[c * 8]);
#pragma unroll
    for (int c = tid; c < BN * 4; c += 256)
      gl16(Bb + (n0 + (c >> 2)) * 1024 + k0 + (c & 3) * 8, &lsB[c * 8]);
    __syncthreads();  // drains vmcnt (global_load_lds) per compiler barrier semantics
    bf16x8 af[TM], bfr[TN];
#pragma unroll
    for (int i = 0; i < TM; i++)
      af[i] = *(const bf16x8*)&lsA[(wm + i * 16 + lm) * 32 + quad * 8];
#pragma unroll
    for (int j = 0; j < TN; j++)
      bfr[j] = *(const bf16x8*)&lsB[(wn + j * 16 + lm) * 32 + quad * 8];
#pragma unroll
    for (int i = 0; i < TM; i++)
#pragma unroll
      for (int j = 0; j < TN; j++)
        acc[i][j] = __builtin_amdgcn_mfma_f32_16x16x32_bf16(af[i], bfr[j], acc[i][j], 0, 0, 0);
    __syncthreads();
  }

  if constexpr (TRANSV) {
    // transposed write: VT[(b*16+h)*64 + dh][c] with n = h*64+dh, mb = global row (b*1024+c)
#pragma unroll
    for (int j = 0; j < TN; j++) {
      long n = n0 + wn + j * 16 + lm;
      float bv = bias[n];
      int h = (int)(n >> 6), dh = (int)(n & 63);
#pragma unroll
      for (int i = 0; i < TM; i++) {
        long mb = m0 + wm + i * 16 + quad * 4;
        int bidx = (int)(mb >> 10);
        long c = mb & 1023;
        u16 pk[4];
#pragma unroll
        for (int r = 0; r < 4; r++) pk[r] = f2b(acc[i][j][r] + bv);
        *(uint2*)((u16*)Cb + ((long)(bidx * 16 + h) * 64 + dh) * 1024 + c) = *(uint2*)pk;
      }
    }
  } else {
#pragma unroll
    for (int j = 0; j < TN; j++) {
      long n = n0 + wn + j * 16 + lm;
      float bv = bias ? bias[n] : 0.f;
#pragma unroll
      for (int i = 0; i < TM; i++) {
        long mb = m0 + wm + i * 16 + quad * 4;
#pragma unroll
        for (int r = 0; r < 4; r++) {
          float val = acc[i][j][r] + bv;
          if constexpr (sizeof(TC) == 2) Cb[(mb + r) * 1024 + n] = f2b(val);
          else Cb[(mb + r) * 1024 + n] = val;
        }
      }
    }
  }
}

struct QKVArgs {
  const u16* A[3];
  const u16* B[3];
  const float* b[3];
  u16* C[3];  // C[2] = VT (transposed layout)
};

// q/k/v projections batched over grid.z -> 768 blocks (3 blocks/CU) for overlap.
// z==2 (v) writes its output directly in the per-(b,h)-transposed VT layout.
__global__ __launch_bounds__(256) void gemm_qkv(QKVArgs g) {
  int z = blockIdx.z;
  long m0 = (long)blockIdx.x * 128, n0 = (long)blockIdx.y * 128;
  if (z == 2)
    gemm_core<128, 128, u16, true>(g.A[2], g.B[2], g.b[2], g.C[2], m0, n0);
  else
    gemm_core<128, 128, u16, false>(g.A[z], g.B[z], g.b[z], g.C[z], m0, n0);
}

__global__ __launch_bounds__(256) void gemm_o(const u16* __restrict__ A,
                                              const u16* __restrict__ Bt,
                                              const float* __restrict__ bias,
                                              float* __restrict__ C) {
  gemm_core<128, 128, float, false>(A, Bt, bias, C, (long)blockIdx.x * 128,
                                    (long)blockIdx.y * 128);
}

// ---------------- fused attention v4 ----------------
// grid (64 q-tiles, 64 z). One block: 16 Q-rows x full 1024 keys.
// Swapped QK^T (mfma(K,Q)): lane holds P[q=lm][keys jj*16+quad*4+0..3] -> one 8B
// LDS write per jj, scalar row-sum, 2-shuffle reduce. No max pass (logits range-safe).
// PV on unnormalized P with 4 partial accumulators; late normalize from wreds.
__global__ __launch_bounds__(256) void fused_attn(const u16* __restrict__ QP,
                                                  const u16* __restrict__ KP,
                                                  const u16* __restrict__ VT,
                                                  float* __restrict__ attn,
                                                  u16* __restrict__ CTX) {
  __shared__ __align__(16) u16 P[16 * 1032];  // bf16 unnormalized exp
  __shared__ __align__(16) u16 qt[16 * 72];
  __shared__ float wreds[4][16];

  int z = blockIdx.y;
  int b = z >> 4, h = z & 15;
  long q0 = (long)blockIdx.x * 16;
  int tid = threadIdx.x;
  int wid = tid >> 6, lane = tid & 63;
  int lm = lane & 15, quad = lane >> 4;

  const u16* Qb = QP + (long)b * 1048576 + (long)h * 64;
  const u16* Kb = KP + (long)b * 1048576 + (long)h * 64;
  const u16* Vz = VT + (long)z * 65536;
  float* Az = attn + (long)z * 1048576;

  // stage Q tile 16x64 (bf16)
  if (tid < 128) {
    int row = tid >> 3, col8 = (tid & 7) * 8;
    *(uint4*)&qt[row * 72 + col8] = *(const uint4*)(Qb + (q0 + row) * 1024 + col8);
  }
  __syncthreads();

  bf16x8 qf0 = *(const bf16x8*)&qt[lm * 72 + quad * 8];
  bf16x8 qf1 = *(const bf16x8*)&qt[lm * 72 + 32 + quad * 8];

  int ncol0 = wid * 256;
  float sum = 0.f;
#pragma unroll
  for (int jj = 0; jj < 16; jj++) {
    const u16* kr = Kb + (long)(ncol0 + jj * 16 + lm) * 1024;
    bf16x8 kf0 = *(const bf16x8*)(kr + quad * 8);
    bf16x8 kf1 = *(const bf16x8*)(kr + 32 + quad * 8);
    f32x4 s = (f32x4){0.f, 0.f, 0.f, 0.f};
    __builtin_amdgcn_s_setprio(1);
    // swapped operands: out row <- K-tile row (quad*4+r), out col <- Q row (lm)
    s = __builtin_amdgcn_mfma_f32_16x16x32_bf16(kf0, qf0, s, 0, 0, 0);
    s = __builtin_amdgcn_mfma_f32_16x16x32_bf16(kf1, qf1, s, 0, 0, 0);
    __builtin_amdgcn_s_setprio(0);
    u16 pk[4];
#pragma unroll
    for (int r = 0; r < 4; r++) {
      float x = s[r];
      // branchless erf (Abramowitz-Stegun 7.1.26, |err| <= 1.5e-7)
      float u = 0.70710678118654752f * x;
      float a = fabsf(u);
      float t = __builtin_amdgcn_rcpf(fmaf(0.3275911f, a, 1.0f));
      float p = t * fmaf(t, fmaf(t, fmaf(t, fmaf(t, 1.061405429f, -1.453152027f),
                                         1.421413741f), -0.284496736f), 0.254829592f);
      float eq = __expf(-a * a);
      float erfa = fmaf(-p, eq, 1.0f);
      float erfu = copysignf(erfa, u);
      float hx = 0.0625f * x;                 // 0.5*x*0.125
      float logit = fmaf(hx, erfu, hx);       // gelu(x)*0.125
      float e = __expf(logit);                // no max-subtraction (range-safe)
      sum += e;
      pk[r] = f2b(e);
    }
    // lane owns P[q=lm][keys ncol0+jj*16+quad*4 .. +3]: one vectorized 8B write
    *(uint2*)&P[lm * 1032 + ncol0 + jj * 16 + quad * 4] = *(uint2*)pk;
  }

  // row-sum for row lm: combine the 4 quad-lanes, then 4 waves via LDS
  sum += __shfl_xor(sum, 16);
  sum += __shfl_xor(sum, 32);
  if (lane < 16) wreds[wid][lane] = sum;
  __syncthreads();

  // attn write: thread t owns cols 4t..4t+3 of every row; coalesced f32x4 nt stores.
  // inv computed on the fly from wreds (LDS broadcast reads).
#pragma unroll
  for (int r = 0; r < 16; r++) {
    float inv = __builtin_amdgcn_rcpf(wreds[0][r] + wreds[1][r] + wreds[2][r] + wreds[3][r]);
    uint2 raw = *(const uint2*)&P[r * 1032 + tid * 4];
    u16* pr = (u16*)&raw;
    f32x4 o;
    o[0] = b2f(pr[0]) * inv;
    o[1] = b2f(pr[1]) * inv;
    o[2] = b2f(pr[2]) * inv;
    o[3] = b2f(pr[3]) * inv;
    __builtin_nontemporal_store(o, (f32x4*)(Az + (q0 + r) * 1024 + tid * 4));
  }

  // ---- P·V on unnormalized P: wave wid owns dh tile [wid*16, wid*16+16) ----
  {
    f32x4 a0 = (f32x4){0.f, 0.f, 0.f, 0.f};
    f32x4 a1 = a0, a2 = a0, a3 = a0;
    const u16* Vrow = Vz + (long)(wid * 16 + lm) * 1024;
#pragma unroll 2
    for (int kc = 0; kc < 1024; kc += 128) {
      bf16x8 p0 = *(const bf16x8*)&P[lm * 1032 + kc + quad * 8];
      bf16x8 v0 = *(const bf16x8*)(Vrow + kc + quad * 8);
      bf16x8 p1 = *(const bf16x8*)&P[lm * 1032 + kc + 32 + quad * 8];
      bf16x8 v1 = *(const bf16x8*)(Vrow + kc + 32 + quad * 8);
      bf16x8 p2 = *(const bf16x8*)&P[lm * 1032 + kc + 64 + quad * 8];
      bf16x8 v2 = *(const bf16x8*)(Vrow + kc + 64 + quad * 8);
      bf16x8 p3 = *(const bf16x8*)&P[lm * 1032 + kc + 96 + quad * 8];
      bf16x8 v3 = *(const bf16x8*)(Vrow + kc + 96 + quad * 8);
      __builtin_amdgcn_s_setprio(1);
      a0 = __builtin_amdgcn_mfma_f32_16x16x32_bf16(p0, v0, a0, 0, 0, 0);
      a1 = __builtin_amdgcn_mfma_f32_16x16x32_bf16(p1, v1, a1, 0, 0, 0);
      a2 = __builtin_amdgcn_mfma_f32_16x16x32_bf16(p2, v2, a2, 0, 0, 0);
      a3 = __builtin_amdgcn_mfma_f32_16x16x32_bf16(p3, v3, a3, 0, 0, 0);
      __builtin_amdgcn_s_setprio(0);
    }
    f32x4 acc = (a0 + a1) + (a2 + a3);
    int n = wid * 16 + lm;
    u16* Cb = CTX + (long)b * 1048576 + (long)h * 64;
#pragma unroll
    for (int r = 0; r < 4; r++) {
      int row = quad * 4 + r;
      float inv = __builtin_amdgcn_rcpf(wreds[0][row] + wreds[1][row] +
                                        wreds[2][row] + wreds[3][row]);
      Cb[(q0 + row) * 1024 + n] = f2b(acc[r] * inv);  // late normalize
    }
  }
}

// ---------------- row-wise L2 normalize (fp32) ----------------
__global__ __launch_bounds__(256) void l2norm_kernel(const float* __restrict__ o,
                                                     float* __restrict__ out) {
  long base = (long)blockIdx.x * 1024;
  int t = threadIdx.x;
  float4 raw = *(const float4*)(o + base + t * 4);
  float v[4] = {raw.x, raw.y, raw.z, raw.w};
  float ss = 0.f;
#pragma unroll
  for (int i = 0; i < 4; i++) ss += v[i] * v[i];
  ss = wsum(ss);
  __shared__ float red[4];
  int wid = t >> 6;
  if ((t & 63) == 0) red[wid] = ss;
  __syncthreads();
  ss = red[0] + red[1] + red[2] + red[3];
  float inv = 1.f / fmaxf(sqrtf(ss), 1e-12f);
  float4 outr = {v[0] * inv, v[1] * inv, v[2] * inv, v[3] * inv};
  *(float4*)(out + base + t * 4) = outr;
}

extern "C" void kernel_launch(void* const* d_in, const int* in_sizes, int n_in,
                              void* d_out, int out_size, void* d_ws, size_t ws_size,
                              hipStream_t stream) {
  const float* q = (const float*)d_in[0];
  const float* k = (const float*)d_in[1];
  const float* v = (const float*)d_in[2];
  const float* ln_k_g = (const float*)d_in[3];
  const float* ln_k_b = (const float*)d_in[4];
  const float* ln_v_g = (const float*)d_in[5];
  const float* ln_v_b = (const float*)d_in[6];
  const float* Wq = (const float*)d_in[7];
  const float* bq = (const float*)d_in[8];
  const float* Wk = (const float*)d_in[9];
  const float* bk = (const float*)d_in[10];
  const float* Wv = (const float*)d_in[11];
  const float* bv_ = (const float*)d_in[12];
  const float* Wo = (const float*)d_in[13];
  const float* bo = (const float*)d_in[14];

  const long MEG = 1024 * 1024;
  u16* ws16 = (u16*)d_ws;
  u16* LNK = ws16;                 // dead after qkv gemm; reused as CTX
  u16* LNV = ws16 + 4 * MEG;       // dead after qkv gemm
  u16* WQT = ws16 + 8 * MEG;
  u16* WKT = ws16 + 9 * MEG;
  u16* WVT = ws16 + 10 * MEG;
  u16* WOT = ws16 + 11 * MEG;      // alive until final proj
  u16* QP  = ws16 + 12 * MEG;      // dead after fused -> OO (fp32, 12M..20M u16)
  u16* KP  = ws16 + 16 * MEG;      // dead after fused
  u16* VT  = ws16 + 24 * MEG;      // written transposed by gemm_qkv z==2
  u16* QB  = ws16 + 28 * MEG;      // q cast to bf16; dead after qkv gemm
  u16* CTX = LNK;
  float* OO = (float*)(ws16 + 12 * MEG);

  float* out = (float*)d_out;
  float* attn = out + 4 * MEG;

  // q cast + LN(k) + LN(v) in one launch
  prep_kernel<<<12288, 256, 0, stream>>>(q, k, v, ln_k_g, ln_k_b, ln_v_g, ln_v_b, QB, LNK, LNV);

  // 4 weight transposes in one launch
  transpose_w4<<<dim3(32, 32, 4), 256, 0, stream>>>(Wq, Wk, Wv, Wo, WQT, WKT, WVT, WOT);

  // q/k/v projections batched (768 blocks = 3 blocks/CU); v written directly transposed
  QKVArgs ga;
  ga.A[0] = QB;  ga.A[1] = LNK; ga.A[2] = LNV;
  ga.B[0] = WQT; ga.B[1] = WKT; ga.B[2] = WVT;
  ga.b[0] = bq;  ga.b[1] = bk;  ga.b[2] = bv_;
  ga.C[0] = QP;  ga.C[1] = KP;  ga.C[2] = VT;
  gemm_qkv<<<dim3(32, 8, 3), 256, 0, stream>>>(ga);

  // fused scores+gelu+softmax+attn+PV
  fused_attn<<<dim3(64, 64), 256, 0, stream>>>(QP, KP, VT, attn, CTX);

  // output projection + bias -> fp32
  gemm_o<<<dim3(32, 8), 256, 0, stream>>>(CTX, WOT, bo, OO);

  l2norm_kernel<<<4096, 256, 0, stream>>>(OO, out);
}